// Round 10
// baseline (206.098 us; speedup 1.0000x reference)
//
#include <hip/hip_runtime.h>
#include <hip/hip_bf16.h>

// Problem constants (match reference)
#define NN 50000
#define EE 800000
#define EP (EE + NN)        // edges + self loops = 850000
#define DIN 128
#define HID 32
#define HEADS 8
#define C1 (HEADS * HID)    // 256
#define DOUT 16
#define NW1 3125            // gemm1 waves: 50000/16
#define SH 8                // bucket shift: 256 nodes/bucket
#define NB 196              // ceil(50000/256)
#define CAP 8192            // per-bucket ebuf capacity (mean 4352, sigma~66)
#define EPT 8               // edges per thread in bucket pass
#define BBLK (256 * EPT)    // 2048 edges per block
#define GB ((NW1 * 64 + 255) / 256)        // 782 gemm1 blocks
#define BB ((EP + BBLK - 1) / BBLK)        // 416 bucket blocks

typedef __attribute__((ext_vector_type(8))) short short8;   // 8 bf16 (4 VGPRs)
typedef __attribute__((ext_vector_type(4))) float float4v;  // MFMA C/D
typedef __attribute__((ext_vector_type(2))) float float2v;  // fp8 cvt result

__device__ inline unsigned short f2bf(float f) {
    __hip_bfloat16 b = __float2bfloat16(f);
    return *reinterpret_cast<unsigned short*>(&b);
}
__device__ inline float bflo(unsigned u) {
    union { unsigned int i; float f; } x;
    x.i = u << 16;
    return x.f;
}
__device__ inline float bfhi(unsigned u) {
    union { unsigned int i; float f; } x;
    x.i = u & 0xffff0000u;
    return x.f;
}
__device__ inline float bf2f(unsigned short u) {
    union { unsigned int i; float f; } x;
    x.i = ((unsigned int)u) << 16;
    return x.f;
}

// ---------------------------------------------------------------------------
// prep: gemm1 A-fragment image (17 tiles) + TRANSPOSED W2 (W2t[col][ch],
// f32 -- R24: gives the fused agg1 epilogue 16 B lane-stride coalesced
// loads; R20's failure was 256 B lane-stride on raw W2) + zero cntb.
// ---------------------------------------------------------------------------
__global__ void k_prepfw(const float* __restrict__ W1, const float* __restrict__ a1s,
                         const float* __restrict__ a1d, const float* __restrict__ W2,
                         unsigned short* __restrict__ w1frag,
                         float* __restrict__ W2t,
                         int* __restrict__ cntb) {
    int i = blockIdx.x * 256 + threadIdx.x;
    if (blockIdx.x == 0 && threadIdx.x < NB) cntb[threadIdx.x] = 0;
    if (i < 17 * 2048) {
        int j = i & 7, lane = (i >> 3) & 63, s = (i >> 9) & 3, c = i >> 11;
        int q = lane >> 4, m = lane & 15;
        int k = s * 32 + q * 8 + j;
        float val;
        if (c < 16) {
            val = W1[k * C1 + c * 16 + m];
        } else {
            int h = m & 7;
            const float* av = (m < 8) ? a1s : a1d;
            float acc = 0.f;
            #pragma unroll
            for (int j2 = 0; j2 < 32; j2++)
                acc += W1[k * C1 + h * 32 + j2] * av[h * 32 + j2];
            val = acc;
        }
        w1frag[i] = f2bf(val);
    } else if (i < 17 * 2048 + DOUT * C1) {
        int j2 = i - 17 * 2048;
        int col = j2 >> 8, ch = j2 & 255;
        W2t[col * C1 + ch] = W2[ch * DOUT + col];
    }
}

// ---------------------------------------------------------------------------
// Merged launch: gemm1 (blocks [0,GB)) runs CONCURRENTLY with the edge
// bucketing pass (blocks [GB, GB+BB)).
// ---------------------------------------------------------------------------
__global__ __launch_bounds__(256) void k_g1bkt(const float* __restrict__ x,
                                               const unsigned short* __restrict__ w1frag,
                                               unsigned char* __restrict__ h1f8,
                                               float* __restrict__ al1sd,
                                               unsigned short* __restrict__ al1s8,
                                               const int* __restrict__ ei,
                                               int* __restrict__ cntb,
                                               unsigned* __restrict__ ebuf) {
    __shared__ int hist[4][NB];
    __shared__ int base[4][NB];
    int bid = blockIdx.x;
    if (bid < GB) {
        // ---- gemm1 path (MFMA, operand-swapped; fp8 h1 + fp32/bf16 logits) ----
        int wid = (bid * 256 + threadIdx.x) >> 6;
        int lane = threadIdx.x & 63;
        if (wid >= NW1) return;
        int nb = wid * 16;
        int m = lane & 15, quad = lane >> 4;
        const float* xrow = x + (nb + m) * DIN;

        float4 xf[8];
        #pragma unroll
        for (int s = 0; s < 4; s++) {
            xf[2 * s]     = *(const float4*)(xrow + s * 32 + quad * 8);
            xf[2 * s + 1] = *(const float4*)(xrow + s * 32 + quad * 8 + 4);
        }
        short8 bfr[4];
        #pragma unroll
        for (int s = 0; s < 4; s++) {
            unsigned short* bp = (unsigned short*)&bfr[s];
            float4 f0 = xf[2 * s], f1 = xf[2 * s + 1];
            bp[0] = f2bf(f0.x); bp[1] = f2bf(f0.y); bp[2] = f2bf(f0.z); bp[3] = f2bf(f0.w);
            bp[4] = f2bf(f1.x); bp[5] = f2bf(f1.y); bp[6] = f2bf(f1.z); bp[7] = f2bf(f1.w);
        }

        float4v acc[17];
        #pragma unroll
        for (int c = 0; c < 17; c++) acc[c] = (float4v){0.f, 0.f, 0.f, 0.f};

        #pragma unroll
        for (int s = 0; s < 4; s++) {
            const unsigned short* fp = w1frag + (s * 64 + lane) * 8;
            #pragma unroll
            for (int c = 0; c < 17; c++) {
                short8 afrag = *(const short8*)(fp + c * 2048);
                acc[c] = __builtin_amdgcn_mfma_f32_16x16x32_bf16(afrag, bfr[s], acc[c], 0, 0, 0);
            }
        }

        int node = nb + m;
        #pragma unroll
        for (int c = 0; c < 16; c++) {
            unsigned pk = 0;
            pk = __builtin_amdgcn_cvt_pk_fp8_f32(acc[c][0], acc[c][1], pk, false);
            pk = __builtin_amdgcn_cvt_pk_fp8_f32(acc[c][2], acc[c][3], pk, true);
            *(unsigned*)(h1f8 + node * C1 + c * 16 + quad * 4) = pk;
        }
        *(float4*)(al1sd + node * 16 + quad * 4) =
            make_float4(acc[16][0], acc[16][1], acc[16][2], acc[16][3]);
        if (quad < 2) {   // src logits (rows 0-7) packed bf16 -- 16 B/node table
            uint2 pk;
            pk.x = (unsigned)f2bf(acc[16][0]) | ((unsigned)f2bf(acc[16][1]) << 16);
            pk.y = (unsigned)f2bf(acc[16][2]) | ((unsigned)f2bf(acc[16][3]) << 16);
            *(uint2*)(al1s8 + node * 8 + quad * 4) = pk;
        }
    } else {
        // ---- bucket path: bucket edges by dst>>8; entry (src<<8)|(dst&255) ----
        int t = threadIdx.x;
        int wave = t >> 6;
        for (int i = t; i < 4 * NB; i += 256) ((int*)hist)[i] = 0;
        __syncthreads();
        int e0 = (bid - GB) * BBLK;
        int s[EPT], d[EPT], r[EPT];
        #pragma unroll
        for (int j = 0; j < EPT; j++) {
            int e = e0 + j * 256 + t;
            int ss = 0, dd = -1;
            if (e < EE) { ss = ei[e]; dd = ei[EE + e]; }
            else if (e < EP) { ss = e - EE; dd = ss; }   // self loop
            s[j] = ss; d[j] = dd;
            if (dd >= 0) r[j] = atomicAdd(&hist[wave][dd >> SH], 1);
        }
        __syncthreads();
        if (t < NB) {
            int h0 = hist[0][t], h1 = hist[1][t], h2 = hist[2][t], h3 = hist[3][t];
            int tot = h0 + h1 + h2 + h3;
            int bb = tot ? atomicAdd(&cntb[t], tot) : 0;
            base[0][t] = bb;
            base[1][t] = bb + h0;
            base[2][t] = bb + h0 + h1;
            base[3][t] = bb + h0 + h1 + h2;
        }
        __syncthreads();
        #pragma unroll
        for (int j = 0; j < EPT; j++) {
            if (d[j] >= 0) {
                int b = d[j] >> SH;
                ebuf[b * CAP + base[wave][b] + r[j]] =
                    ((unsigned)s[j] << SH) | (unsigned)(d[j] & 255);
            }
        }
    }
}

// ---------------------------------------------------------------------------
// CSR pass 2: one block per bucket; LDS count -> scan -> rank scatter.
// ---------------------------------------------------------------------------
__global__ __launch_bounds__(1024) void k_csr(const int* __restrict__ cntb,
                                              const unsigned* __restrict__ ebuf,
                                              int* __restrict__ row_ptr,
                                              int* __restrict__ esrc) {
    __shared__ int sdeg[256];
    __shared__ int wtot[4];
    __shared__ int bpart[4];
    int b = blockIdx.x;
    int t = threadIdx.x;
    int lane = t & 63, wave = t >> 6;
    int nodes0 = b << SH;
    if (t < 256) sdeg[t] = 0;
    if (t < 256) {
        int v = (t < b) ? cntb[t] : 0;
        #pragma unroll
        for (int off = 1; off < 64; off <<= 1) v += __shfl_xor(v, off, 64);
        if (lane == 0) bpart[wave] = v;
    }
    __syncthreads();
    int baseS = bpart[0] + bpart[1] + bpart[2] + bpart[3];
    int cnt = cntb[b];
    const unsigned* eb = ebuf + b * CAP;
    for (int i = t; i < cnt; i += 1024)
        atomicAdd(&sdeg[eb[i] & 255], 1);
    __syncthreads();
    int v = (t < 256) ? sdeg[t] : 0;
    int inc = v;
    #pragma unroll
    for (int off = 1; off < 64; off <<= 1) {
        int u = __shfl_up(inc, off, 64);
        if (lane >= off) inc += u;
    }
    if (t < 256 && lane == 63) wtot[wave] = inc;
    __syncthreads();
    if (wave == 0 && lane < 4) {
        int w = wtot[lane];
        int iw = w;
        #pragma unroll
        for (int off = 1; off < 4; off <<= 1) {
            int u = __shfl_up(iw, off, 64);
            if (lane >= off) iw += u;
        }
        wtot[lane] = iw - w;   // exclusive
    }
    __syncthreads();
    int excl = inc - v + ((t < 256) ? wtot[wave] : 0);
    __syncthreads();
    if (t < 256) {
        sdeg[t] = excl;
        int node = nodes0 + t;
        if (node < NN) row_ptr[node] = baseS + excl;
    }
    __syncthreads();
    for (int i = t; i < cnt; i += 1024) {
        unsigned e = eb[i];
        int pos = atomicAdd(&sdeg[e & 255], 1);
        esrc[baseS + pos] = (int)(e >> SH);
    }
    if (b == 0 && t == 0) row_ptr[NN] = EP;
}

// ---------------------------------------------------------------------------
// agg1 + FUSED gemm2 (R24): gather loop = proven R22 shape (hoisted producer
// gathers). Epilogue = R20's HW-VERIFIED-CORRECT c[16]+reduce-scatter math
// (Round 6 passed absmax 0.03125), but with W2t (transposed, f32): lane L
// loads W2t[col*256+4L..] -- 16 B lane stride, coalesced, L1-resident 16 KB
// table. R20's 117 us came from 256 B-stride raw-W2 loads (64 lines/instr).
// Eliminates k_gemm2 and the 25.6 MB helu_b write+read entirely.
// ---------------------------------------------------------------------------
__global__ __launch_bounds__(256) void k_agg1(const int* __restrict__ row_ptr,
                                              const int* __restrict__ esrc,
                                              const unsigned short* __restrict__ al1s8,
                                              const float* __restrict__ al1sd,
                                              const unsigned char* __restrict__ h1f8,
                                              const float* __restrict__ b1,
                                              const float* __restrict__ W2t,
                                              const float* __restrict__ a2s,
                                              const float* __restrict__ a2d,
                                              unsigned short* __restrict__ h2b,
                                              float* __restrict__ al2s,
                                              float* __restrict__ al2d) {
    int L = threadIdx.x & 63;
    int d = __builtin_amdgcn_readfirstlane((int)((blockIdx.x * 256 + threadIdx.x) >> 6));
    int start = row_ptr[d], end = row_ptr[d + 1];
    const int Lofs = L * 4;
    const int hprod = L & 7;             // producer head
    const int egrp  = L >> 3;            // producer edge-slot / consumer head
    float ald_p = al1sd[d * 16 + 8 + hprod];
    float denom = 0.f;
    float4 acc = make_float4(0.f, 0.f, 0.f, 0.f);

    for (int base = start; base < end; base += 32) {
        int cnt = min(32, end - base);            // wave-uniform
        int sval = d;
        if (L < cnt) sval = esrc[base + L];
        // --- hoisted producer gathers: all 4 groups' src logits in flight ---
        float asv0, asv1, asv2, asv3;
        {
            int sp0 = __shfl(sval, 0 * 8 + egrp, 64);
            int sp1 = __shfl(sval, 1 * 8 + egrp, 64);
            int sp2 = __shfl(sval, 2 * 8 + egrp, 64);
            int sp3 = __shfl(sval, 3 * 8 + egrp, 64);
            asv0 = bf2f(al1s8[sp0 * 8 + hprod]);
            asv1 = bf2f(al1s8[sp1 * 8 + hprod]);
            asv2 = bf2f(al1s8[sp2 * 8 + hprod]);
            asv3 = bf2f(al1s8[sp3 * 8 + hprod]);
        }
        #define AGG1_GROUP(K, ASV)                                              \
        if (cnt > (K) * 8) {                                                    \
            float e = (ASV) + ald_p;                                            \
            e = e > 0.f ? e : 0.2f * e;                                         \
            float w = ((K) * 8 + egrp < cnt) ? __expf(e) : 0.f;                 \
            unsigned v[8];                                                      \
            float xw[8];                                                        \
            _Pragma("unroll")                                                   \
            for (int j = 0; j < 8; j++) {                                       \
                int sj = __builtin_amdgcn_readlane(sval, (K) * 8 + j);          \
                v[j] = *(const unsigned*)(h1f8 + sj * C1 + Lofs);               \
                xw[j] = __shfl(w, j * 8 + egrp, 64);                            \
            }                                                                   \
            _Pragma("unroll")                                                   \
            for (int j = 0; j < 8; j++) {                                       \
                float2v a = __builtin_amdgcn_cvt_pk_f32_fp8(v[j], false);       \
                float2v b = __builtin_amdgcn_cvt_pk_f32_fp8(v[j], true);        \
                float xj = xw[j];                                               \
                denom += xj;                                                    \
                acc.x += xj * a.x; acc.y += xj * a.y;                           \
                acc.z += xj * b.x; acc.w += xj * b.y;                           \
            }                                                                   \
        }
        AGG1_GROUP(0, asv0)
        AGG1_GROUP(1, asv1)
        AGG1_GROUP(2, asv2)
        AGG1_GROUP(3, asv3)
        #undef AGG1_GROUP
    }
    float inv = 1.0f / (denom + 1e-16f);
    float4 bv = *(const float4*)(b1 + Lofs);
    float o0 = acc.x * inv + bv.x;
    float o1 = acc.y * inv + bv.y;
    float o2 = acc.z * inv + bv.z;
    float o3 = acc.w * inv + bv.w;
    o0 = o0 > 0.f ? o0 : __expf(o0) - 1.0f;
    o1 = o1 > 0.f ? o1 : __expf(o1) - 1.0f;
    o2 = o2 > 0.f ? o2 : __expf(o2) - 1.0f;
    o3 = o3 > 0.f ? o3 : __expf(o3) - 1.0f;

    // ---- fused gemm2: h2[d][0..15] = helu_row(256) . W2(256x16) ----
    // lane L holds channels 4L..4L+3; coalesced W2t loads (16 B lane stride)
    float c[16];
    {
        const float* wt = W2t + 4 * L;
        #pragma unroll
        for (int k = 0; k < 16; k++) {
            float4 wr = *(const float4*)(wt + k * C1);
            c[k] = o0 * wr.x + o1 * wr.y + o2 * wr.z + o3 * wr.w;
        }
    }
    // stage 1: sum the 4-lane channel classes (bits 0,1)
    #pragma unroll
    for (int k = 0; k < 16; k++) {
        c[k] += __shfl_xor(c[k], 1, 64);
        c[k] += __shfl_xor(c[k], 2, 64);
    }
    // stage 2: reduce-scatter halving over bits 2..5
    int b2 = (L >> 2) & 1, b3 = (L >> 3) & 1, b4 = (L >> 4) & 1, b5 = (L >> 5) & 1;
    #pragma unroll
    for (int k = 0; k < 8; k++) {
        float give = b2 ? c[k] : c[k + 8];
        float keep = b2 ? c[k + 8] : c[k];
        c[k] = keep + __shfl_xor(give, 4, 64);
    }
    #pragma unroll
    for (int k = 0; k < 4; k++) {
        float give = b3 ? c[k] : c[k + 4];
        float keep = b3 ? c[k + 4] : c[k];
        c[k] = keep + __shfl_xor(give, 8, 64);
    }
    #pragma unroll
    for (int k = 0; k < 2; k++) {
        float give = b4 ? c[k] : c[k + 2];
        float keep = b4 ? c[k + 2] : c[k];
        c[k] = keep + __shfl_xor(give, 16, 64);
    }
    {
        float give = b5 ? c[0] : c[1];
        float keep = b5 ? c[1] : c[0];
        c[0] = keep + __shfl_xor(give, 32, 64);
    }
    int col = (b2 << 3) | (b3 << 2) | (b4 << 1) | b5;
    float cf = c[0];
    // al2 logits: each 16-lane tree (fixed bits 0,1) holds all 16 columns
    float ps = cf * a2s[col];
    float pd = cf * a2d[col];
    ps += __shfl_xor(ps, 4, 64);  ps += __shfl_xor(ps, 8, 64);
    ps += __shfl_xor(ps, 16, 64); ps += __shfl_xor(ps, 32, 64);
    pd += __shfl_xor(pd, 4, 64);  pd += __shfl_xor(pd, 8, 64);
    pd += __shfl_xor(pd, 16, 64); pd += __shfl_xor(pd, 32, 64);
    if (L == 0) {
        al2s[d] = ps;
        al2d[d] = pd;
    }
    if ((L & 3) == 0) h2b[d * DOUT + col] = f2bf(cf);
}

// ---------------------------------------------------------------------------
// agg2 + bias + log_softmax (R23 zero-LDS form, unchanged).
// ---------------------------------------------------------------------------
__global__ __launch_bounds__(256) void k_agg2(const int* __restrict__ row_ptr,
                                              const int* __restrict__ esrc,
                                              const unsigned short* __restrict__ h2b,
                                              const float* __restrict__ al2s,
                                              const float* __restrict__ al2d,
                                              const float* __restrict__ b2,
                                              float* __restrict__ out) {
    int L = threadIdx.x & 63;
    int n = __builtin_amdgcn_readfirstlane((int)((blockIdx.x * 256 + threadIdx.x) >> 6));
    int p = L & 7, g = L >> 3;          // channel-pair, edge-slot
    int start = row_ptr[n], end = row_ptr[n + 1];
    float ald = al2d[n];
    float acc0 = 0.f, acc1 = 0.f, denom = 0.f;

    for (int base = start; base < end; base += 64) {
        int cnt = min(64, end - base);            // wave-uniform
        int sval = n; float w = 0.f;
        if (L < cnt) {
            sval = esrc[base + L];
            float e = al2s[sval] + ald;
            e = e > 0.f ? e : 0.2f * e;
            w = __expf(e);
        }
        unsigned v0, v1, v2, v3, v4, v5, v6, v7;
        float w0, w1, w2, w3, w4, w5, w6, w7;
        #define AGG2_LOAD(K, V, W)                                             \
        if (cnt > (K) * 8) {                                                   \
            int ss = __shfl(sval, (K) * 8 + g, 64);                            \
            W = __shfl(w, (K) * 8 + g, 64);                                    \
            V = *(const unsigned*)(h2b + ss * DOUT + p * 2);                   \
        }
        AGG2_LOAD(0, v0, w0) AGG2_LOAD(1, v1, w1)
        AGG2_LOAD(2, v2, w2) AGG2_LOAD(3, v3, w3)
        AGG2_LOAD(4, v4, w4) AGG2_LOAD(5, v5, w5)
        AGG2_LOAD(6, v6, w6) AGG2_LOAD(7, v7, w7)
        #undef AGG2_LOAD
        #define AGG2_ACC(K, V, W)                                              \
        if (cnt > (K) * 8) {                                                   \
            acc0 += W * bflo(V); acc1 += W * bfhi(V); denom += W;              \
        }
        AGG2_ACC(0, v0, w0) AGG2_ACC(1, v1, w1)
        AGG2_ACC(2, v2, w2) AGG2_ACC(3, v3, w3)
        AGG2_ACC(4, v4, w4) AGG2_ACC(5, v5, w5)
        AGG2_ACC(6, v6, w6) AGG2_ACC(7, v7, w7)
        #undef AGG2_ACC
    }
    acc0 += __shfl_xor(acc0, 8, 64);  acc0 += __shfl_xor(acc0, 16, 64);  acc0 += __shfl_xor(acc0, 32, 64);
    acc1 += __shfl_xor(acc1, 8, 64);  acc1 += __shfl_xor(acc1, 16, 64);  acc1 += __shfl_xor(acc1, 32, 64);
    denom += __shfl_xor(denom, 8, 64); denom += __shfl_xor(denom, 16, 64); denom += __shfl_xor(denom, 32, 64);
    float inv = 1.0f / (denom + 1e-16f);
    float2 bv = *(const float2*)(b2 + p * 2);
    float val0 = acc0 * inv + bv.x;
    float val1 = acc1 * inv + bv.y;
    float m = fmaxf(val0, val1);
    #pragma unroll
    for (int mm = 1; mm < 8; mm <<= 1) m = fmaxf(m, __shfl_xor(m, mm, 64));
    float se = __expf(val0 - m) + __expf(val1 - m);
    #pragma unroll
    for (int mm = 1; mm < 8; mm <<= 1) se += __shfl_xor(se, mm, 64);
    float lse = m + __logf(se);
    if (L < 8) {
        float2 o = make_float2(val0 - lse, val1 - lse);
        *(float2*)(out + n * DOUT + p * 2) = o;
    }
}

// ---------------------------------------------------------------------------
extern "C" void kernel_launch(void* const* d_in, const int* in_sizes, int n_in,
                              void* d_out, int out_size, void* d_ws, size_t ws_size,
                              hipStream_t stream) {
    const float* x   = (const float*)d_in[0];
    const int*   ei  = (const int*)d_in[1];
    const float* W1  = (const float*)d_in[2];
    const float* a1s = (const float*)d_in[3];
    const float* a1d = (const float*)d_in[4];
    const float* b1  = (const float*)d_in[5];
    const float* W2  = (const float*)d_in[6];
    const float* a2s = (const float*)d_in[7];
    const float* a2d = (const float*)d_in[8];
    const float* b2  = (const float*)d_in[9];
    float* outp = (float*)d_out;

    // workspace layout (helu_b + w2frag eliminated by the fusion)
    unsigned char* h1f8    = (unsigned char*)d_ws;       // N*256 fp8 e4m3 (12.8 MB)
    unsigned* ebuf = (unsigned*)(h1f8 + NN * C1);        // NB*CAP uint (6.4 MB)
    unsigned short* h2b    = (unsigned short*)(ebuf + NB * CAP);  // N*16 bf16
    unsigned short* w1frag = h2b + NN * DOUT;            // 34816 bf16
    unsigned short* al1s8  = w1frag + 17 * 2048;         // N*8 bf16 (src logits)
    float* W2t   = (float*)(al1s8 + NN * 8);             // 16*256 f32 (transposed W2)
    float* al1sd = W2t + DOUT * C1;                      // N*16 fp32
    float* al2sb = al1sd + NN * 16;                      // N
    float* al2db = al2sb + NN;                           // N
    int* row_ptr = (int*)(al2db + NN);                   // N+1
    int* esrc    = row_ptr + NN + 1;                     // EP
    int* cntb    = esrc + EP;                            // NB

    // chain: prep -> {gemm1 || bucket} -> csr -> agg1(+gemm2 fused) -> agg2
    k_prepfw<<<(17 * 2048 + DOUT * C1 + 255) / 256, 256, 0, stream>>>(W1, a1s, a1d, W2, w1frag, W2t, cntb);
    k_g1bkt<<<GB + BB, 256, 0, stream>>>(x, w1frag, h1f8, al1sd, al1s8, ei, cntb, ebuf);
    k_csr<<<NB, 1024, 0, stream>>>(cntb, ebuf, row_ptr, esrc);
    k_agg1<<<12500, 256, 0, stream>>>(row_ptr, esrc, al1s8, al1sd, h1f8, b1, W2t, a2s, a2d, h2b, al2sb, al2db);
    k_agg2<<<(NN * 64 + 255) / 256, 256, 0, stream>>>(row_ptr, esrc, h2b, al2sb, al2db, b2, outp);
}

// Round 11
// 202.053 us; speedup vs baseline: 1.0200x; 1.0200x over previous
//
#include <hip/hip_runtime.h>
#include <hip/hip_bf16.h>

// Problem constants (match reference)
#define NN 50000
#define EE 800000
#define EP (EE + NN)        // edges + self loops = 850000
#define DIN 128
#define HID 32
#define HEADS 8
#define C1 (HEADS * HID)    // 256
#define DOUT 16
#define NW1 3125            // gemm1/gemm2 waves: 50000/16
#define SH 8                // bucket shift: 256 nodes/bucket
#define NB 196              // ceil(50000/256)
#define CAP 8192            // per-bucket ebuf capacity (mean 4352, sigma~66)
#define EPT 4               // edges per thread in bucket pass (R25: 8->4, 2x blocks)
#define BBLK (256 * EPT)    // 1024 edges per block
#define GB ((NW1 * 64 + 255) / 256)        // 782 gemm1 blocks
#define BB ((EP + BBLK - 1) / BBLK)        // 831 bucket blocks

typedef __attribute__((ext_vector_type(8))) short short8;   // 8 bf16 (4 VGPRs)
typedef __attribute__((ext_vector_type(4))) float float4v;  // MFMA C/D
typedef __attribute__((ext_vector_type(2))) float float2v;  // fp8 cvt result

__device__ inline unsigned short f2bf(float f) {
    __hip_bfloat16 b = __float2bfloat16(f);
    return *reinterpret_cast<unsigned short*>(&b);
}
__device__ inline float bflo(unsigned u) {
    union { unsigned int i; float f; } x;
    x.i = u << 16;
    return x.f;
}
__device__ inline float bfhi(unsigned u) {
    union { unsigned int i; float f; } x;
    x.i = u & 0xffff0000u;
    return x.f;
}
__device__ inline float bf2f(unsigned short u) {
    union { unsigned int i; float f; } x;
    x.i = ((unsigned int)u) << 16;
    return x.f;
}

// ---------------------------------------------------------------------------
// prep: gemm1 A-fragment image (17 tiles) + gemm2 B-fragment image + zero
// cntb.
// ---------------------------------------------------------------------------
__global__ void k_prepfw(const float* __restrict__ W1, const float* __restrict__ a1s,
                         const float* __restrict__ a1d, const float* __restrict__ W2,
                         unsigned short* __restrict__ w1frag,
                         unsigned short* __restrict__ w2frag,
                         int* __restrict__ cntb) {
    int i = blockIdx.x * 256 + threadIdx.x;
    if (blockIdx.x == 0 && threadIdx.x < NB) cntb[threadIdx.x] = 0;
    if (i < 17 * 2048) {
        int j = i & 7, lane = (i >> 3) & 63, s = (i >> 9) & 3, c = i >> 11;
        int q = lane >> 4, m = lane & 15;
        int k = s * 32 + q * 8 + j;
        float val;
        if (c < 16) {
            val = W1[k * C1 + c * 16 + m];
        } else {
            int h = m & 7;
            const float* av = (m < 8) ? a1s : a1d;
            float acc = 0.f;
            #pragma unroll
            for (int j2 = 0; j2 < 32; j2++)
                acc += W1[k * C1 + h * 32 + j2] * av[h * 32 + j2];
            val = acc;
        }
        w1frag[i] = f2bf(val);
    } else if (i < 17 * 2048 + 8 * 512) {
        int j2 = i - 17 * 2048;
        int jj = j2 & 7, lane = (j2 >> 3) & 63, s = j2 >> 9;
        int q = lane >> 4, m = lane & 15;
        w2frag[j2] = f2bf(W2[(s * 32 + q * 8 + jj) * DOUT + m]);
    }
}

// ---------------------------------------------------------------------------
// Merged launch (R25: BUCKET FIRST). R9 profile showed gemm1's blocks fill
// the machine then retire in ~5 us, leaving the latency-bound bucket path as
// a 6.5-waves/CU tail (occupancy 15.7%) for most of the 42 us. Bucket blocks
// [0,BB) now dispatch first; gemm1 blocks [BB,BB+GB) overlap behind them.
// EPT 8->4 doubles bucket-block count for the same work.
// ---------------------------------------------------------------------------
__global__ __launch_bounds__(256) void k_g1bkt(const float* __restrict__ x,
                                               const unsigned short* __restrict__ w1frag,
                                               unsigned char* __restrict__ h1f8,
                                               float* __restrict__ al1sd,
                                               unsigned short* __restrict__ al1s8,
                                               const int* __restrict__ ei,
                                               int* __restrict__ cntb,
                                               unsigned* __restrict__ ebuf) {
    __shared__ int hist[4][NB];
    __shared__ int base[4][NB];
    int bid = blockIdx.x;
    if (bid >= BB) {
        // ---- gemm1 path (MFMA, operand-swapped; fp8 h1 + fp32/bf16 logits) ----
        int wid = ((bid - BB) * 256 + threadIdx.x) >> 6;
        int lane = threadIdx.x & 63;
        if (wid >= NW1) return;
        int nb = wid * 16;
        int m = lane & 15, quad = lane >> 4;
        const float* xrow = x + (nb + m) * DIN;

        float4 xf[8];
        #pragma unroll
        for (int s = 0; s < 4; s++) {
            xf[2 * s]     = *(const float4*)(xrow + s * 32 + quad * 8);
            xf[2 * s + 1] = *(const float4*)(xrow + s * 32 + quad * 8 + 4);
        }
        short8 bfr[4];
        #pragma unroll
        for (int s = 0; s < 4; s++) {
            unsigned short* bp = (unsigned short*)&bfr[s];
            float4 f0 = xf[2 * s], f1 = xf[2 * s + 1];
            bp[0] = f2bf(f0.x); bp[1] = f2bf(f0.y); bp[2] = f2bf(f0.z); bp[3] = f2bf(f0.w);
            bp[4] = f2bf(f1.x); bp[5] = f2bf(f1.y); bp[6] = f2bf(f1.z); bp[7] = f2bf(f1.w);
        }

        float4v acc[17];
        #pragma unroll
        for (int c = 0; c < 17; c++) acc[c] = (float4v){0.f, 0.f, 0.f, 0.f};

        #pragma unroll
        for (int s = 0; s < 4; s++) {
            const unsigned short* fp = w1frag + (s * 64 + lane) * 8;
            #pragma unroll
            for (int c = 0; c < 17; c++) {
                short8 afrag = *(const short8*)(fp + c * 2048);
                acc[c] = __builtin_amdgcn_mfma_f32_16x16x32_bf16(afrag, bfr[s], acc[c], 0, 0, 0);
            }
        }

        int node = nb + m;
        #pragma unroll
        for (int c = 0; c < 16; c++) {
            unsigned pk = 0;
            pk = __builtin_amdgcn_cvt_pk_fp8_f32(acc[c][0], acc[c][1], pk, false);
            pk = __builtin_amdgcn_cvt_pk_fp8_f32(acc[c][2], acc[c][3], pk, true);
            *(unsigned*)(h1f8 + node * C1 + c * 16 + quad * 4) = pk;
        }
        *(float4*)(al1sd + node * 16 + quad * 4) =
            make_float4(acc[16][0], acc[16][1], acc[16][2], acc[16][3]);
        if (quad < 2) {   // src logits (rows 0-7) packed bf16 -- 16 B/node table
            uint2 pk;
            pk.x = (unsigned)f2bf(acc[16][0]) | ((unsigned)f2bf(acc[16][1]) << 16);
            pk.y = (unsigned)f2bf(acc[16][2]) | ((unsigned)f2bf(acc[16][3]) << 16);
            *(uint2*)(al1s8 + node * 8 + quad * 4) = pk;
        }
    } else {
        // ---- bucket path: bucket edges by dst>>8; entry (src<<8)|(dst&255) ----
        int t = threadIdx.x;
        int wave = t >> 6;
        for (int i = t; i < 4 * NB; i += 256) ((int*)hist)[i] = 0;
        __syncthreads();
        int e0 = bid * BBLK;
        int s[EPT], d[EPT], r[EPT];
        #pragma unroll
        for (int j = 0; j < EPT; j++) {
            int e = e0 + j * 256 + t;
            int ss = 0, dd = -1;
            if (e < EE) { ss = ei[e]; dd = ei[EE + e]; }
            else if (e < EP) { ss = e - EE; dd = ss; }   // self loop
            s[j] = ss; d[j] = dd;
            if (dd >= 0) r[j] = atomicAdd(&hist[wave][dd >> SH], 1);
        }
        __syncthreads();
        if (t < NB) {
            int h0 = hist[0][t], h1 = hist[1][t], h2 = hist[2][t], h3 = hist[3][t];
            int tot = h0 + h1 + h2 + h3;
            int bb = tot ? atomicAdd(&cntb[t], tot) : 0;
            base[0][t] = bb;
            base[1][t] = bb + h0;
            base[2][t] = bb + h0 + h1;
            base[3][t] = bb + h0 + h1 + h2;
        }
        __syncthreads();
        #pragma unroll
        for (int j = 0; j < EPT; j++) {
            if (d[j] >= 0) {
                int b = d[j] >> SH;
                ebuf[b * CAP + base[wave][b] + r[j]] =
                    ((unsigned)s[j] << SH) | (unsigned)(d[j] & 255);
            }
        }
    }
}

// ---------------------------------------------------------------------------
// CSR pass 2: one block per bucket; LDS count -> scan -> rank scatter.
// ---------------------------------------------------------------------------
__global__ __launch_bounds__(1024) void k_csr(const int* __restrict__ cntb,
                                              const unsigned* __restrict__ ebuf,
                                              int* __restrict__ row_ptr,
                                              int* __restrict__ esrc) {
    __shared__ int sdeg[256];
    __shared__ int wtot[4];
    __shared__ int bpart[4];
    int b = blockIdx.x;
    int t = threadIdx.x;
    int lane = t & 63, wave = t >> 6;
    int nodes0 = b << SH;
    if (t < 256) sdeg[t] = 0;
    if (t < 256) {
        int v = (t < b) ? cntb[t] : 0;
        #pragma unroll
        for (int off = 1; off < 64; off <<= 1) v += __shfl_xor(v, off, 64);
        if (lane == 0) bpart[wave] = v;
    }
    __syncthreads();
    int baseS = bpart[0] + bpart[1] + bpart[2] + bpart[3];
    int cnt = cntb[b];
    const unsigned* eb = ebuf + b * CAP;
    for (int i = t; i < cnt; i += 1024)
        atomicAdd(&sdeg[eb[i] & 255], 1);
    __syncthreads();
    int v = (t < 256) ? sdeg[t] : 0;
    int inc = v;
    #pragma unroll
    for (int off = 1; off < 64; off <<= 1) {
        int u = __shfl_up(inc, off, 64);
        if (lane >= off) inc += u;
    }
    if (t < 256 && lane == 63) wtot[wave] = inc;
    __syncthreads();
    if (wave == 0 && lane < 4) {
        int w = wtot[lane];
        int iw = w;
        #pragma unroll
        for (int off = 1; off < 4; off <<= 1) {
            int u = __shfl_up(iw, off, 64);
            if (lane >= off) iw += u;
        }
        wtot[lane] = iw - w;   // exclusive
    }
    __syncthreads();
    int excl = inc - v + ((t < 256) ? wtot[wave] : 0);
    __syncthreads();
    if (t < 256) {
        sdeg[t] = excl;
        int node = nodes0 + t;
        if (node < NN) row_ptr[node] = baseS + excl;
    }
    __syncthreads();
    for (int i = t; i < cnt; i += 1024) {
        unsigned e = eb[i];
        int pos = atomicAdd(&sdeg[e & 255], 1);
        esrc[baseS + pos] = (int)(e >> SH);
    }
    if (b == 0 && t == 0) row_ptr[NN] = EP;
}

// ---------------------------------------------------------------------------
// agg1 (R22, unchanged): hoisted producer gathers + readlane consumer.
// ---------------------------------------------------------------------------
__global__ __launch_bounds__(256) void k_agg1(const int* __restrict__ row_ptr,
                                              const int* __restrict__ esrc,
                                              const unsigned short* __restrict__ al1s8,
                                              const float* __restrict__ al1sd,
                                              const unsigned char* __restrict__ h1f8,
                                              const float* __restrict__ b1,
                                              unsigned short* __restrict__ helu_b) {
    int L = threadIdx.x & 63;
    int d = __builtin_amdgcn_readfirstlane((int)((blockIdx.x * 256 + threadIdx.x) >> 6));
    int start = row_ptr[d], end = row_ptr[d + 1];
    const int Lofs = L * 4;
    const int hprod = L & 7;             // producer head
    const int egrp  = L >> 3;            // producer edge-slot / consumer head
    float ald_p = al1sd[d * 16 + 8 + hprod];
    float denom = 0.f;
    float4 acc = make_float4(0.f, 0.f, 0.f, 0.f);

    for (int base = start; base < end; base += 32) {
        int cnt = min(32, end - base);            // wave-uniform
        int sval = d;
        if (L < cnt) sval = esrc[base + L];
        // --- hoisted producer gathers: all 4 groups' src logits in flight ---
        float asv0, asv1, asv2, asv3;
        {
            int sp0 = __shfl(sval, 0 * 8 + egrp, 64);
            int sp1 = __shfl(sval, 1 * 8 + egrp, 64);
            int sp2 = __shfl(sval, 2 * 8 + egrp, 64);
            int sp3 = __shfl(sval, 3 * 8 + egrp, 64);
            asv0 = bf2f(al1s8[sp0 * 8 + hprod]);
            asv1 = bf2f(al1s8[sp1 * 8 + hprod]);
            asv2 = bf2f(al1s8[sp2 * 8 + hprod]);
            asv3 = bf2f(al1s8[sp3 * 8 + hprod]);
        }
        #define AGG1_GROUP(K, ASV)                                              \
        if (cnt > (K) * 8) {                                                    \
            float e = (ASV) + ald_p;                                            \
            e = e > 0.f ? e : 0.2f * e;                                         \
            float w = ((K) * 8 + egrp < cnt) ? __expf(e) : 0.f;                 \
            unsigned v[8];                                                      \
            float xw[8];                                                        \
            _Pragma("unroll")                                                   \
            for (int j = 0; j < 8; j++) {                                       \
                int sj = __builtin_amdgcn_readlane(sval, (K) * 8 + j);          \
                v[j] = *(const unsigned*)(h1f8 + sj * C1 + Lofs);               \
                xw[j] = __shfl(w, j * 8 + egrp, 64);                            \
            }                                                                   \
            _Pragma("unroll")                                                   \
            for (int j = 0; j < 8; j++) {                                       \
                float2v a = __builtin_amdgcn_cvt_pk_f32_fp8(v[j], false);       \
                float2v b = __builtin_amdgcn_cvt_pk_f32_fp8(v[j], true);        \
                float xj = xw[j];                                               \
                denom += xj;                                                    \
                acc.x += xj * a.x; acc.y += xj * a.y;                           \
                acc.z += xj * b.x; acc.w += xj * b.y;                           \
            }                                                                   \
        }
        AGG1_GROUP(0, asv0)
        AGG1_GROUP(1, asv1)
        AGG1_GROUP(2, asv2)
        AGG1_GROUP(3, asv3)
        #undef AGG1_GROUP
    }
    float inv = 1.0f / (denom + 1e-16f);
    float4 bv = *(const float4*)(b1 + Lofs);
    float o0 = acc.x * inv + bv.x;
    float o1 = acc.y * inv + bv.y;
    float o2 = acc.z * inv + bv.z;
    float o3 = acc.w * inv + bv.w;
    o0 = o0 > 0.f ? o0 : __expf(o0) - 1.0f;
    o1 = o1 > 0.f ? o1 : __expf(o1) - 1.0f;
    o2 = o2 > 0.f ? o2 : __expf(o2) - 1.0f;
    o3 = o3 > 0.f ? o3 : __expf(o3) - 1.0f;
    uint2 pk;
    pk.x = (unsigned)f2bf(o0) | ((unsigned)f2bf(o1) << 16);
    pk.y = (unsigned)f2bf(o2) | ((unsigned)f2bf(o3) << 16);
    *(uint2*)(helu_b + d * C1 + Lofs) = pk;
}

// ---------------------------------------------------------------------------
// GEMM2 via MFMA + fused al2 epilogue (w2frag fragment-image B loads).
// ---------------------------------------------------------------------------
__global__ __launch_bounds__(256) void k_gemm2(const unsigned short* __restrict__ helu_b,
                                               const unsigned short* __restrict__ w2frag,
                                               const float* __restrict__ a2s,
                                               const float* __restrict__ a2d,
                                               unsigned short* __restrict__ h2b,
                                               float* __restrict__ al2s,
                                               float* __restrict__ al2d) {
    int wid = (blockIdx.x * 256 + threadIdx.x) >> 6;
    int lane = threadIdx.x & 63;
    int nb = wid * 16;
    if (nb >= NN) return;
    int m = lane & 15, quad = lane >> 4;

    const unsigned short* wp2 = w2frag + lane * 8;
    float4v acc = {0.f, 0.f, 0.f, 0.f};
    const unsigned short* arow = helu_b + (nb + m) * C1 + quad * 8;
    #pragma unroll
    for (int s = 0; s < 8; s++) {
        short8 afrag = *(const short8*)(arow + s * 32);
        short8 bfrag = *(const short8*)(wp2 + s * 512);
        acc = __builtin_amdgcn_mfma_f32_16x16x32_bf16(afrag, bfrag, acc, 0, 0, 0);
    }

    float as_c = a2s[m], ad_c = a2d[m];
    #pragma unroll
    for (int r = 0; r < 4; r++) {
        int node = nb + quad * 4 + r;
        float val = acc[r];
        h2b[node * DOUT + m] = f2bf(val);
        float ps = val * as_c;
        float pd = val * ad_c;
        ps += __shfl_xor(ps, 1, 64); ps += __shfl_xor(ps, 2, 64);
        ps += __shfl_xor(ps, 4, 64); ps += __shfl_xor(ps, 8, 64);
        pd += __shfl_xor(pd, 1, 64); pd += __shfl_xor(pd, 2, 64);
        pd += __shfl_xor(pd, 4, 64); pd += __shfl_xor(pd, 8, 64);
        if (m == 0) {
            al2s[node] = ps;
            al2d[node] = pd;
        }
    }
}

// ---------------------------------------------------------------------------
// agg2 + bias + log_softmax (R23 zero-LDS form, unchanged).
// ---------------------------------------------------------------------------
__global__ __launch_bounds__(256) void k_agg2(const int* __restrict__ row_ptr,
                                              const int* __restrict__ esrc,
                                              const unsigned short* __restrict__ h2b,
                                              const float* __restrict__ al2s,
                                              const float* __restrict__ al2d,
                                              const float* __restrict__ b2,
                                              float* __restrict__ out) {
    int L = threadIdx.x & 63;
    int n = __builtin_amdgcn_readfirstlane((int)((blockIdx.x * 256 + threadIdx.x) >> 6));
    int p = L & 7, g = L >> 3;          // channel-pair, edge-slot
    int start = row_ptr[n], end = row_ptr[n + 1];
    float ald = al2d[n];
    float acc0 = 0.f, acc1 = 0.f, denom = 0.f;

    for (int base = start; base < end; base += 64) {
        int cnt = min(64, end - base);            // wave-uniform
        int sval = n; float w = 0.f;
        if (L < cnt) {
            sval = esrc[base + L];
            float e = al2s[sval] + ald;
            e = e > 0.f ? e : 0.2f * e;
            w = __expf(e);
        }
        unsigned v0, v1, v2, v3, v4, v5, v6, v7;
        float w0, w1, w2, w3, w4, w5, w6, w7;
        #define AGG2_LOAD(K, V, W)                                             \
        if (cnt > (K) * 8) {                                                   \
            int ss = __shfl(sval, (K) * 8 + g, 64);                            \
            W = __shfl(w, (K) * 8 + g, 64);                                    \
            V = *(const unsigned*)(h2b + ss * DOUT + p * 2);                   \
        }
        AGG2_LOAD(0, v0, w0) AGG2_LOAD(1, v1, w1)
        AGG2_LOAD(2, v2, w2) AGG2_LOAD(3, v3, w3)
        AGG2_LOAD(4, v4, w4) AGG2_LOAD(5, v5, w5)
        AGG2_LOAD(6, v6, w6) AGG2_LOAD(7, v7, w7)
        #undef AGG2_LOAD
        #define AGG2_ACC(K, V, W)                                              \
        if (cnt > (K) * 8) {                                                   \
            acc0 += W * bflo(V); acc1 += W * bfhi(V); denom += W;              \
        }
        AGG2_ACC(0, v0, w0) AGG2_ACC(1, v1, w1)
        AGG2_ACC(2, v2, w2) AGG2_ACC(3, v3, w3)
        AGG2_ACC(4, v4, w4) AGG2_ACC(5, v5, w5)
        AGG2_ACC(6, v6, w6) AGG2_ACC(7, v7, w7)
        #undef AGG2_ACC
    }
    acc0 += __shfl_xor(acc0, 8, 64);  acc0 += __shfl_xor(acc0, 16, 64);  acc0 += __shfl_xor(acc0, 32, 64);
    acc1 += __shfl_xor(acc1, 8, 64);  acc1 += __shfl_xor(acc1, 16, 64);  acc1 += __shfl_xor(acc1, 32, 64);
    denom += __shfl_xor(denom, 8, 64); denom += __shfl_xor(denom, 16, 64); denom += __shfl_xor(denom, 32, 64);
    float inv = 1.0f / (denom + 1e-16f);
    float2 bv = *(const float2*)(b2 + p * 2);
    float val0 = acc0 * inv + bv.x;
    float val1 = acc1 * inv + bv.y;
    float m = fmaxf(val0, val1);
    #pragma unroll
    for (int mm = 1; mm < 8; mm <<= 1) m = fmaxf(m, __shfl_xor(m, mm, 64));
    float se = __expf(val0 - m) + __expf(val1 - m);
    #pragma unroll
    for (int mm = 1; mm < 8; mm <<= 1) se += __shfl_xor(se, mm, 64);
    float lse = m + __logf(se);
    if (L < 8) {
        float2 o = make_float2(val0 - lse, val1 - lse);
        *(float2*)(out + n * DOUT + p * 2) = o;
    }
}

// ---------------------------------------------------------------------------
extern "C" void kernel_launch(void* const* d_in, const int* in_sizes, int n_in,
                              void* d_out, int out_size, void* d_ws, size_t ws_size,
                              hipStream_t stream) {
    const float* x   = (const float*)d_in[0];
    const int*   ei  = (const int*)d_in[1];
    const float* W1  = (const float*)d_in[2];
    const float* a1s = (const float*)d_in[3];
    const float* a1d = (const float*)d_in[4];
    const float* b1  = (const float*)d_in[5];
    const float* W2  = (const float*)d_in[6];
    const float* a2s = (const float*)d_in[7];
    const float* a2d = (const float*)d_in[8];
    const float* b2  = (const float*)d_in[9];
    float* outp = (float*)d_out;

    // workspace layout
    unsigned char* h1f8    = (unsigned char*)d_ws;       // N*256 fp8 e4m3 (12.8 MB)
    unsigned short* helu_b = (unsigned short*)(h1f8 + NN * C1);  // N*256 bf16 (25.6 MB)
    unsigned short* h2b    = helu_b + NN * C1;           // N*16 bf16
    unsigned short* w2frag = h2b + NN * DOUT;            // 4096 bf16 (frag order)
    unsigned short* w1frag = w2frag + 8 * 512;           // 34816 bf16
    unsigned short* al1s8  = w1frag + 17 * 2048;         // N*8 bf16 (src logits)
    float* al1sd = (float*)(al1s8 + NN * 8);             // N*16 fp32
    float* al2sb = al1sd + NN * 16;                      // N
    float* al2db = al2sb + NN;                           // N
    int* row_ptr = (int*)(al2db + NN);                   // N+1
    int* esrc    = row_ptr + NN + 1;                     // EP
    int* cntb    = esrc + EP;                            // NB
    // ebuf (packed ints, 6.4 MB) aliases helu_b (25.6 MB); consumed by k_csr
    // before agg1 writes helu_b -- stream ordering guarantees it.
    unsigned* ebuf = (unsigned*)helu_b;                  // NB * CAP uint

    // chain: prep -> {bucket || gemm1} -> csr -> agg1 -> gemm2 -> agg2
    k_prepfw<<<(17 * 2048 + 8 * 512 + 255) / 256, 256, 0, stream>>>(W1, a1s, a1d, W2, w1frag, w2frag, cntb);
    k_g1bkt<<<BB + GB, 256, 0, stream>>>(x, w1frag, h1f8, al1sd, al1s8, ei, cntb, ebuf);
    k_csr<<<NB, 1024, 0, stream>>>(cntb, ebuf, row_ptr, esrc);
    k_agg1<<<12500, 256, 0, stream>>>(row_ptr, esrc, al1s8, al1sd, h1f8, b1, helu_b);
    k_gemm2<<<(NW1 * 64 + 255) / 256, 256, 0, stream>>>(helu_b, w2frag, a2s, a2d, h2b, al2sb, al2db);
    k_agg2<<<(NN * 64 + 255) / 256, 256, 0, stream>>>(row_ptr, esrc, h2b, al2sb, al2db, b2, outp);
}

// Round 12
// 199.061 us; speedup vs baseline: 1.0354x; 1.0150x over previous
//
#include <hip/hip_runtime.h>
#include <hip/hip_bf16.h>

// Problem constants (match reference)
#define NN 50000
#define EE 800000
#define EP (EE + NN)        // edges + self loops = 850000
#define DIN 128
#define HID 32
#define HEADS 8
#define C1 (HEADS * HID)    // 256
#define DOUT 16
#define NW1 3125            // gemm1/gemm2 waves: 50000/16
#define SH 8                // bucket shift: 256 nodes/bucket
#define NB 196              // ceil(50000/256)
#define CAP 8192            // per-bucket ebuf capacity (mean 4352, sigma~66)
#define EPT 32              // edges per thread (R26: 8->32 -- 104 blocks, 4x less cntb contention)
#define BBLK (256 * EPT)    // 8192 edges per block
#define GB ((NW1 * 64 + 255) / 256)        // 782 gemm1 blocks
#define BB ((EP + BBLK - 1) / BBLK)        // 104 bucket blocks

typedef __attribute__((ext_vector_type(8))) short short8;   // 8 bf16 (4 VGPRs)
typedef __attribute__((ext_vector_type(4))) float float4v;  // MFMA C/D
typedef __attribute__((ext_vector_type(2))) float float2v;  // fp8 cvt result

__device__ inline unsigned short f2bf(float f) {
    __hip_bfloat16 b = __float2bfloat16(f);
    return *reinterpret_cast<unsigned short*>(&b);
}
__device__ inline float bflo(unsigned u) {
    union { unsigned int i; float f; } x;
    x.i = u << 16;
    return x.f;
}
__device__ inline float bfhi(unsigned u) {
    union { unsigned int i; float f; } x;
    x.i = u & 0xffff0000u;
    return x.f;
}
__device__ inline float bf2f(unsigned short u) {
    union { unsigned int i; float f; } x;
    x.i = ((unsigned int)u) << 16;
    return x.f;
}

// ---------------------------------------------------------------------------
// prep: gemm1 A-fragment image (17 tiles) + gemm2 B-fragment image + zero
// cntb.
// ---------------------------------------------------------------------------
__global__ void k_prepfw(const float* __restrict__ W1, const float* __restrict__ a1s,
                         const float* __restrict__ a1d, const float* __restrict__ W2,
                         unsigned short* __restrict__ w1frag,
                         unsigned short* __restrict__ w2frag,
                         int* __restrict__ cntb) {
    int i = blockIdx.x * 256 + threadIdx.x;
    if (blockIdx.x == 0 && threadIdx.x < NB) cntb[threadIdx.x] = 0;
    if (i < 17 * 2048) {
        int j = i & 7, lane = (i >> 3) & 63, s = (i >> 9) & 3, c = i >> 11;
        int q = lane >> 4, m = lane & 15;
        int k = s * 32 + q * 8 + j;
        float val;
        if (c < 16) {
            val = W1[k * C1 + c * 16 + m];
        } else {
            int h = m & 7;
            const float* av = (m < 8) ? a1s : a1d;
            float acc = 0.f;
            #pragma unroll
            for (int j2 = 0; j2 < 32; j2++)
                acc += W1[k * C1 + h * 32 + j2] * av[h * 32 + j2];
            val = acc;
        }
        w1frag[i] = f2bf(val);
    } else if (i < 17 * 2048 + 8 * 512) {
        int j2 = i - 17 * 2048;
        int jj = j2 & 7, lane = (j2 >> 3) & 63, s = j2 >> 9;
        int q = lane >> 4, m = lane & 15;
        w2frag[j2] = f2bf(W2[(s * 32 + q * 8 + jj) * DOUT + m]);
    }
}

// ---------------------------------------------------------------------------
// Merged launch: gemm1 (blocks [0,GB)) runs CONCURRENTLY with the edge
// bucketing pass (blocks [GB, GB+BB)). R26 bucket path: array-free 3-phase
// (histogram -> base via ONE global atomic per (block,bucket), now only 104
// per address vs R23's 416 -- the cntb atomic queue WAS the 26+ us cost --
// -> re-read edges + LDS-cursor rank scatter). No per-thread edge arrays,
// so EPT=32 adds no VGPR pressure.
// ---------------------------------------------------------------------------
__global__ __launch_bounds__(256) void k_g1bkt(const float* __restrict__ x,
                                               const unsigned short* __restrict__ w1frag,
                                               unsigned char* __restrict__ h1f8,
                                               float* __restrict__ al1sd,
                                               unsigned short* __restrict__ al1s8,
                                               const int* __restrict__ ei,
                                               int* __restrict__ cntb,
                                               unsigned* __restrict__ ebuf) {
    __shared__ int hist[4][NB];
    __shared__ int base[4][NB];
    int bid = blockIdx.x;
    if (bid < GB) {
        // ---- gemm1 path (MFMA, operand-swapped; fp8 h1 + fp32/bf16 logits) ----
        int wid = (bid * 256 + threadIdx.x) >> 6;
        int lane = threadIdx.x & 63;
        if (wid >= NW1) return;
        int nb = wid * 16;
        int m = lane & 15, quad = lane >> 4;
        const float* xrow = x + (nb + m) * DIN;

        float4 xf[8];
        #pragma unroll
        for (int s = 0; s < 4; s++) {
            xf[2 * s]     = *(const float4*)(xrow + s * 32 + quad * 8);
            xf[2 * s + 1] = *(const float4*)(xrow + s * 32 + quad * 8 + 4);
        }
        short8 bfr[4];
        #pragma unroll
        for (int s = 0; s < 4; s++) {
            unsigned short* bp = (unsigned short*)&bfr[s];
            float4 f0 = xf[2 * s], f1 = xf[2 * s + 1];
            bp[0] = f2bf(f0.x); bp[1] = f2bf(f0.y); bp[2] = f2bf(f0.z); bp[3] = f2bf(f0.w);
            bp[4] = f2bf(f1.x); bp[5] = f2bf(f1.y); bp[6] = f2bf(f1.z); bp[7] = f2bf(f1.w);
        }

        float4v acc[17];
        #pragma unroll
        for (int c = 0; c < 17; c++) acc[c] = (float4v){0.f, 0.f, 0.f, 0.f};

        #pragma unroll
        for (int s = 0; s < 4; s++) {
            const unsigned short* fp = w1frag + (s * 64 + lane) * 8;
            #pragma unroll
            for (int c = 0; c < 17; c++) {
                short8 afrag = *(const short8*)(fp + c * 2048);
                acc[c] = __builtin_amdgcn_mfma_f32_16x16x32_bf16(afrag, bfr[s], acc[c], 0, 0, 0);
            }
        }

        int node = nb + m;
        #pragma unroll
        for (int c = 0; c < 16; c++) {
            unsigned pk = 0;
            pk = __builtin_amdgcn_cvt_pk_fp8_f32(acc[c][0], acc[c][1], pk, false);
            pk = __builtin_amdgcn_cvt_pk_fp8_f32(acc[c][2], acc[c][3], pk, true);
            *(unsigned*)(h1f8 + node * C1 + c * 16 + quad * 4) = pk;
        }
        *(float4*)(al1sd + node * 16 + quad * 4) =
            make_float4(acc[16][0], acc[16][1], acc[16][2], acc[16][3]);
        if (quad < 2) {   // src logits (rows 0-7) packed bf16 -- 16 B/node table
            uint2 pk;
            pk.x = (unsigned)f2bf(acc[16][0]) | ((unsigned)f2bf(acc[16][1]) << 16);
            pk.y = (unsigned)f2bf(acc[16][2]) | ((unsigned)f2bf(acc[16][3]) << 16);
            *(uint2*)(al1s8 + node * 8 + quad * 4) = pk;
        }
    } else {
        // ---- bucket path (R26, array-free 3-phase) ----
        int t = threadIdx.x;
        int wave = t >> 6;
        for (int i = t; i < 4 * NB; i += 256) ((int*)hist)[i] = 0;
        __syncthreads();
        int e0 = (bid - GB) * BBLK;
        // phase A: histogram only
        for (int j = 0; j < EPT; j++) {
            int e = e0 + j * 256 + t;
            if (e < EE) {
                int dd = ei[EE + e];
                atomicAdd(&hist[wave][dd >> SH], 1);
            } else if (e < EP) {
                int dd = e - EE;
                atomicAdd(&hist[wave][dd >> SH], 1);
            }
        }
        __syncthreads();
        // phase B: one global atomic per (block,bucket) -- 104 per address
        if (t < NB) {
            int h0 = hist[0][t], h1 = hist[1][t], h2 = hist[2][t], h3 = hist[3][t];
            int tot = h0 + h1 + h2 + h3;
            int bb = tot ? atomicAdd(&cntb[t], tot) : 0;
            base[0][t] = bb;
            base[1][t] = bb + h0;
            base[2][t] = bb + h0 + h1;
            base[3][t] = bb + h0 + h1 + h2;
        }
        __syncthreads();
        // phase C: re-read edges (L2-hot), rank via LDS cursor on base
        for (int j = 0; j < EPT; j++) {
            int e = e0 + j * 256 + t;
            int ss, dd = -1;
            if (e < EE) { ss = ei[e]; dd = ei[EE + e]; }
            else if (e < EP) { ss = e - EE; dd = ss; }
            if (dd >= 0) {
                int b = dd >> SH;
                int pos = atomicAdd(&base[wave][b], 1);
                ebuf[b * CAP + pos] = ((unsigned)ss << SH) | (unsigned)(dd & 255);
            }
        }
    }
}

// ---------------------------------------------------------------------------
// CSR pass 2: one block per bucket; LDS count -> scan -> rank scatter.
// ---------------------------------------------------------------------------
__global__ __launch_bounds__(1024) void k_csr(const int* __restrict__ cntb,
                                              const unsigned* __restrict__ ebuf,
                                              int* __restrict__ row_ptr,
                                              int* __restrict__ esrc) {
    __shared__ int sdeg[256];
    __shared__ int wtot[4];
    __shared__ int bpart[4];
    int b = blockIdx.x;
    int t = threadIdx.x;
    int lane = t & 63, wave = t >> 6;
    int nodes0 = b << SH;
    if (t < 256) sdeg[t] = 0;
    if (t < 256) {
        int v = (t < b) ? cntb[t] : 0;
        #pragma unroll
        for (int off = 1; off < 64; off <<= 1) v += __shfl_xor(v, off, 64);
        if (lane == 0) bpart[wave] = v;
    }
    __syncthreads();
    int baseS = bpart[0] + bpart[1] + bpart[2] + bpart[3];
    int cnt = cntb[b];
    const unsigned* eb = ebuf + b * CAP;
    for (int i = t; i < cnt; i += 1024)
        atomicAdd(&sdeg[eb[i] & 255], 1);
    __syncthreads();
    int v = (t < 256) ? sdeg[t] : 0;
    int inc = v;
    #pragma unroll
    for (int off = 1; off < 64; off <<= 1) {
        int u = __shfl_up(inc, off, 64);
        if (lane >= off) inc += u;
    }
    if (t < 256 && lane == 63) wtot[wave] = inc;
    __syncthreads();
    if (wave == 0 && lane < 4) {
        int w = wtot[lane];
        int iw = w;
        #pragma unroll
        for (int off = 1; off < 4; off <<= 1) {
            int u = __shfl_up(iw, off, 64);
            if (lane >= off) iw += u;
        }
        wtot[lane] = iw - w;   // exclusive
    }
    __syncthreads();
    int excl = inc - v + ((t < 256) ? wtot[wave] : 0);
    __syncthreads();
    if (t < 256) {
        sdeg[t] = excl;
        int node = nodes0 + t;
        if (node < NN) row_ptr[node] = baseS + excl;
    }
    __syncthreads();
    for (int i = t; i < cnt; i += 1024) {
        unsigned e = eb[i];
        int pos = atomicAdd(&sdeg[e & 255], 1);
        esrc[baseS + pos] = (int)(e >> SH);
    }
    if (b == 0 && t == 0) row_ptr[NN] = EP;
}

// ---------------------------------------------------------------------------
// agg1 (R22, unchanged): hoisted producer gathers + readlane consumer.
// ---------------------------------------------------------------------------
__global__ __launch_bounds__(256) void k_agg1(const int* __restrict__ row_ptr,
                                              const int* __restrict__ esrc,
                                              const unsigned short* __restrict__ al1s8,
                                              const float* __restrict__ al1sd,
                                              const unsigned char* __restrict__ h1f8,
                                              const float* __restrict__ b1,
                                              unsigned short* __restrict__ helu_b) {
    int L = threadIdx.x & 63;
    int d = __builtin_amdgcn_readfirstlane((int)((blockIdx.x * 256 + threadIdx.x) >> 6));
    int start = row_ptr[d], end = row_ptr[d + 1];
    const int Lofs = L * 4;
    const int hprod = L & 7;             // producer head
    const int egrp  = L >> 3;            // producer edge-slot / consumer head
    float ald_p = al1sd[d * 16 + 8 + hprod];
    float denom = 0.f;
    float4 acc = make_float4(0.f, 0.f, 0.f, 0.f);

    for (int base = start; base < end; base += 32) {
        int cnt = min(32, end - base);            // wave-uniform
        int sval = d;
        if (L < cnt) sval = esrc[base + L];
        // --- hoisted producer gathers: all 4 groups' src logits in flight ---
        float asv0, asv1, asv2, asv3;
        {
            int sp0 = __shfl(sval, 0 * 8 + egrp, 64);
            int sp1 = __shfl(sval, 1 * 8 + egrp, 64);
            int sp2 = __shfl(sval, 2 * 8 + egrp, 64);
            int sp3 = __shfl(sval, 3 * 8 + egrp, 64);
            asv0 = bf2f(al1s8[sp0 * 8 + hprod]);
            asv1 = bf2f(al1s8[sp1 * 8 + hprod]);
            asv2 = bf2f(al1s8[sp2 * 8 + hprod]);
            asv3 = bf2f(al1s8[sp3 * 8 + hprod]);
        }
        #define AGG1_GROUP(K, ASV)                                              \
        if (cnt > (K) * 8) {                                                    \
            float e = (ASV) + ald_p;                                            \
            e = e > 0.f ? e : 0.2f * e;                                         \
            float w = ((K) * 8 + egrp < cnt) ? __expf(e) : 0.f;                 \
            unsigned v[8];                                                      \
            float xw[8];                                                        \
            _Pragma("unroll")                                                   \
            for (int j = 0; j < 8; j++) {                                       \
                int sj = __builtin_amdgcn_readlane(sval, (K) * 8 + j);          \
                v[j] = *(const unsigned*)(h1f8 + sj * C1 + Lofs);               \
                xw[j] = __shfl(w, j * 8 + egrp, 64);                            \
            }                                                                   \
            _Pragma("unroll")                                                   \
            for (int j = 0; j < 8; j++) {                                       \
                float2v a = __builtin_amdgcn_cvt_pk_f32_fp8(v[j], false);       \
                float2v b = __builtin_amdgcn_cvt_pk_f32_fp8(v[j], true);        \
                float xj = xw[j];                                               \
                denom += xj;                                                    \
                acc.x += xj * a.x; acc.y += xj * a.y;                           \
                acc.z += xj * b.x; acc.w += xj * b.y;                           \
            }                                                                   \
        }
        AGG1_GROUP(0, asv0)
        AGG1_GROUP(1, asv1)
        AGG1_GROUP(2, asv2)
        AGG1_GROUP(3, asv3)
        #undef AGG1_GROUP
    }
    float inv = 1.0f / (denom + 1e-16f);
    float4 bv = *(const float4*)(b1 + Lofs);
    float o0 = acc.x * inv + bv.x;
    float o1 = acc.y * inv + bv.y;
    float o2 = acc.z * inv + bv.z;
    float o3 = acc.w * inv + bv.w;
    o0 = o0 > 0.f ? o0 : __expf(o0) - 1.0f;
    o1 = o1 > 0.f ? o1 : __expf(o1) - 1.0f;
    o2 = o2 > 0.f ? o2 : __expf(o2) - 1.0f;
    o3 = o3 > 0.f ? o3 : __expf(o3) - 1.0f;
    uint2 pk;
    pk.x = (unsigned)f2bf(o0) | ((unsigned)f2bf(o1) << 16);
    pk.y = (unsigned)f2bf(o2) | ((unsigned)f2bf(o3) << 16);
    *(uint2*)(helu_b + d * C1 + Lofs) = pk;
}

// ---------------------------------------------------------------------------
// GEMM2 via MFMA + fused al2 epilogue (w2frag fragment-image B loads).
// ---------------------------------------------------------------------------
__global__ __launch_bounds__(256) void k_gemm2(const unsigned short* __restrict__ helu_b,
                                               const unsigned short* __restrict__ w2frag,
                                               const float* __restrict__ a2s,
                                               const float* __restrict__ a2d,
                                               unsigned short* __restrict__ h2b,
                                               float* __restrict__ al2s,
                                               float* __restrict__ al2d) {
    int wid = (blockIdx.x * 256 + threadIdx.x) >> 6;
    int lane = threadIdx.x & 63;
    int nb = wid * 16;
    if (nb >= NN) return;
    int m = lane & 15, quad = lane >> 4;

    const unsigned short* wp2 = w2frag + lane * 8;
    float4v acc = {0.f, 0.f, 0.f, 0.f};
    const unsigned short* arow = helu_b + (nb + m) * C1 + quad * 8;
    #pragma unroll
    for (int s = 0; s < 8; s++) {
        short8 afrag = *(const short8*)(arow + s * 32);
        short8 bfrag = *(const short8*)(wp2 + s * 512);
        acc = __builtin_amdgcn_mfma_f32_16x16x32_bf16(afrag, bfrag, acc, 0, 0, 0);
    }

    float as_c = a2s[m], ad_c = a2d[m];
    #pragma unroll
    for (int r = 0; r < 4; r++) {
        int node = nb + quad * 4 + r;
        float val = acc[r];
        h2b[node * DOUT + m] = f2bf(val);
        float ps = val * as_c;
        float pd = val * ad_c;
        ps += __shfl_xor(ps, 1, 64); ps += __shfl_xor(ps, 2, 64);
        ps += __shfl_xor(ps, 4, 64); ps += __shfl_xor(ps, 8, 64);
        pd += __shfl_xor(pd, 1, 64); pd += __shfl_xor(pd, 2, 64);
        pd += __shfl_xor(pd, 4, 64); pd += __shfl_xor(pd, 8, 64);
        if (m == 0) {
            al2s[node] = ps;
            al2d[node] = pd;
        }
    }
}

// ---------------------------------------------------------------------------
// agg2 + bias + log_softmax (R23 zero-LDS form, unchanged).
// ---------------------------------------------------------------------------
__global__ __launch_bounds__(256) void k_agg2(const int* __restrict__ row_ptr,
                                              const int* __restrict__ esrc,
                                              const unsigned short* __restrict__ h2b,
                                              const float* __restrict__ al2s,
                                              const float* __restrict__ al2d,
                                              const float* __restrict__ b2,
                                              float* __restrict__ out) {
    int L = threadIdx.x & 63;
    int n = __builtin_amdgcn_readfirstlane((int)((blockIdx.x * 256 + threadIdx.x) >> 6));
    int p = L & 7, g = L >> 3;          // channel-pair, edge-slot
    int start = row_ptr[n], end = row_ptr[n + 1];
    float ald = al2d[n];
    float acc0 = 0.f, acc1 = 0.f, denom = 0.f;

    for (int base = start; base < end; base += 64) {
        int cnt = min(64, end - base);            // wave-uniform
        int sval = n; float w = 0.f;
        if (L < cnt) {
            sval = esrc[base + L];
            float e = al2s[sval] + ald;
            e = e > 0.f ? e : 0.2f * e;
            w = __expf(e);
        }
        unsigned v0, v1, v2, v3, v4, v5, v6, v7;
        float w0, w1, w2, w3, w4, w5, w6, w7;
        #define AGG2_LOAD(K, V, W)                                             \
        if (cnt > (K) * 8) {                                                   \
            int ss = __shfl(sval, (K) * 8 + g, 64);                            \
            W = __shfl(w, (K) * 8 + g, 64);                                    \
            V = *(const unsigned*)(h2b + ss * DOUT + p * 2);                   \
        }
        AGG2_LOAD(0, v0, w0) AGG2_LOAD(1, v1, w1)
        AGG2_LOAD(2, v2, w2) AGG2_LOAD(3, v3, w3)
        AGG2_LOAD(4, v4, w4) AGG2_LOAD(5, v5, w5)
        AGG2_LOAD(6, v6, w6) AGG2_LOAD(7, v7, w7)
        #undef AGG2_LOAD
        #define AGG2_ACC(K, V, W)                                              \
        if (cnt > (K) * 8) {                                                   \
            acc0 += W * bflo(V); acc1 += W * bfhi(V); denom += W;              \
        }
        AGG2_ACC(0, v0, w0) AGG2_ACC(1, v1, w1)
        AGG2_ACC(2, v2, w2) AGG2_ACC(3, v3, w3)
        AGG2_ACC(4, v4, w4) AGG2_ACC(5, v5, w5)
        AGG2_ACC(6, v6, w6) AGG2_ACC(7, v7, w7)
        #undef AGG2_ACC
    }
    acc0 += __shfl_xor(acc0, 8, 64);  acc0 += __shfl_xor(acc0, 16, 64);  acc0 += __shfl_xor(acc0, 32, 64);
    acc1 += __shfl_xor(acc1, 8, 64);  acc1 += __shfl_xor(acc1, 16, 64);  acc1 += __shfl_xor(acc1, 32, 64);
    denom += __shfl_xor(denom, 8, 64); denom += __shfl_xor(denom, 16, 64); denom += __shfl_xor(denom, 32, 64);
    float inv = 1.0f / (denom + 1e-16f);
    float2 bv = *(const float2*)(b2 + p * 2);
    float val0 = acc0 * inv + bv.x;
    float val1 = acc1 * inv + bv.y;
    float m = fmaxf(val0, val1);
    #pragma unroll
    for (int mm = 1; mm < 8; mm <<= 1) m = fmaxf(m, __shfl_xor(m, mm, 64));
    float se = __expf(val0 - m) + __expf(val1 - m);
    #pragma unroll
    for (int mm = 1; mm < 8; mm <<= 1) se += __shfl_xor(se, mm, 64);
    float lse = m + __logf(se);
    if (L < 8) {
        float2 o = make_float2(val0 - lse, val1 - lse);
        *(float2*)(out + n * DOUT + p * 2) = o;
    }
}

// ---------------------------------------------------------------------------
extern "C" void kernel_launch(void* const* d_in, const int* in_sizes, int n_in,
                              void* d_out, int out_size, void* d_ws, size_t ws_size,
                              hipStream_t stream) {
    const float* x   = (const float*)d_in[0];
    const int*   ei  = (const int*)d_in[1];
    const float* W1  = (const float*)d_in[2];
    const float* a1s = (const float*)d_in[3];
    const float* a1d = (const float*)d_in[4];
    const float* b1  = (const float*)d_in[5];
    const float* W2  = (const float*)d_in[6];
    const float* a2s = (const float*)d_in[7];
    const float* a2d = (const float*)d_in[8];
    const float* b2  = (const float*)d_in[9];
    float* outp = (float*)d_out;

    // workspace layout
    unsigned char* h1f8    = (unsigned char*)d_ws;       // N*256 fp8 e4m3 (12.8 MB)
    unsigned short* helu_b = (unsigned short*)(h1f8 + NN * C1);  // N*256 bf16 (25.6 MB)
    unsigned short* h2b    = helu_b + NN * C1;           // N*16 bf16
    unsigned short* w2frag = h2b + NN * DOUT;            // 4096 bf16 (frag order)
    unsigned short* w1frag = w2frag + 8 * 512;           // 34816 bf16
    unsigned short* al1s8  = w1frag + 17 * 2048;         // N*8 bf16 (src logits)
    float* al1sd = (float*)(al1s8 + NN * 8);             // N*16 fp32
    float* al2sb = al1sd + NN * 16;                      // N
    float* al2db = al2sb + NN;                           // N
    int* row_ptr = (int*)(al2db + NN);                   // N+1
    int* esrc    = row_ptr + NN + 1;                     // EP
    int* cntb    = esrc + EP;                            // NB
    // ebuf (packed ints, 6.4 MB) aliases helu_b (25.6 MB); consumed by k_csr
    // before agg1 writes helu_b -- stream ordering guarantees it.
    unsigned* ebuf = (unsigned*)helu_b;                  // NB * CAP uint

    // chain: prep -> {gemm1 || bucket} -> csr -> agg1 -> gemm2 -> agg2
    k_prepfw<<<(17 * 2048 + 8 * 512 + 255) / 256, 256, 0, stream>>>(W1, a1s, a1d, W2, w1frag, w2frag, cntb);
    k_g1bkt<<<GB + BB, 256, 0, stream>>>(x, w1frag, h1f8, al1sd, al1s8, ei, cntb, ebuf);
    k_csr<<<NB, 1024, 0, stream>>>(cntb, ebuf, row_ptr, esrc);
    k_agg1<<<12500, 256, 0, stream>>>(row_ptr, esrc, al1s8, al1sd, h1f8, b1, helu_b);
    k_gemm2<<<(NW1 * 64 + 255) / 256, 256, 0, stream>>>(helu_b, w2frag, a2s, a2d, h2b, al2sb, al2db);
    k_agg2<<<(NN * 64 + 255) / 256, 256, 0, stream>>>(row_ptr, esrc, h2b, al2sb, al2db, b2, outp);
}

// Round 13
// 182.777 us; speedup vs baseline: 1.1276x; 1.0891x over previous
//
#include <hip/hip_runtime.h>
#include <hip/hip_bf16.h>

// Problem constants (match reference)
#define NN 50000
#define EE 800000
#define EP (EE + NN)        // edges + self loops = 850000
#define DIN 128
#define HID 32
#define HEADS 8
#define C1 (HEADS * HID)    // 256
#define DOUT 16
#define NW1 3125            // gemm1/gemm2 waves: 50000/16
#define SH 8                // bucket shift: 256 nodes/bucket
#define NB 196              // ceil(50000/256)
#define CAP 8192            // per-bucket ebuf capacity (mean 4352, sigma~66)
#define EPT 8               // edges per thread in bucket pass (R23 proven)
#define BBLK (256 * EPT)    // 2048 edges per block
#define GB ((NW1 * 64 + 255) / 256)        // 782 gemm1 blocks
#define BB ((EP + BBLK - 1) / BBLK)        // 416 bucket blocks
#define CSTR 32             // R27: cntb stride (ints) = one 128B line per bucket
                            // -- 196 consecutive ints pack into ~12 cache lines;
                            // same-line atomics serialize at one L2 bank (6.6k
                            // ops/line-queue ~ 20us). Padding gives 196 queues.

typedef __attribute__((ext_vector_type(8))) short short8;   // 8 bf16 (4 VGPRs)
typedef __attribute__((ext_vector_type(4))) float float4v;  // MFMA C/D
typedef __attribute__((ext_vector_type(2))) float float2v;  // fp8 cvt result

__device__ inline unsigned short f2bf(float f) {
    __hip_bfloat16 b = __float2bfloat16(f);
    return *reinterpret_cast<unsigned short*>(&b);
}
__device__ inline float bflo(unsigned u) {
    union { unsigned int i; float f; } x;
    x.i = u << 16;
    return x.f;
}
__device__ inline float bfhi(unsigned u) {
    union { unsigned int i; float f; } x;
    x.i = u & 0xffff0000u;
    return x.f;
}
__device__ inline float bf2f(unsigned short u) {
    union { unsigned int i; float f; } x;
    x.i = ((unsigned int)u) << 16;
    return x.f;
}

// ---------------------------------------------------------------------------
// prep: gemm1 A-fragment image (17 tiles) + gemm2 B-fragment image + zero
// cntb (line-padded).
// ---------------------------------------------------------------------------
__global__ void k_prepfw(const float* __restrict__ W1, const float* __restrict__ a1s,
                         const float* __restrict__ a1d, const float* __restrict__ W2,
                         unsigned short* __restrict__ w1frag,
                         unsigned short* __restrict__ w2frag,
                         int* __restrict__ cntb) {
    int i = blockIdx.x * 256 + threadIdx.x;
    if (blockIdx.x == 0 && threadIdx.x < NB) cntb[threadIdx.x * CSTR] = 0;
    if (i < 17 * 2048) {
        int j = i & 7, lane = (i >> 3) & 63, s = (i >> 9) & 3, c = i >> 11;
        int q = lane >> 4, m = lane & 15;
        int k = s * 32 + q * 8 + j;
        float val;
        if (c < 16) {
            val = W1[k * C1 + c * 16 + m];
        } else {
            int h = m & 7;
            const float* av = (m < 8) ? a1s : a1d;
            float acc = 0.f;
            #pragma unroll
            for (int j2 = 0; j2 < 32; j2++)
                acc += W1[k * C1 + h * 32 + j2] * av[h * 32 + j2];
            val = acc;
        }
        w1frag[i] = f2bf(val);
    } else if (i < 17 * 2048 + 8 * 512) {
        int j2 = i - 17 * 2048;
        int jj = j2 & 7, lane = (j2 >> 3) & 63, s = j2 >> 9;
        int q = lane >> 4, m = lane & 15;
        w2frag[j2] = f2bf(W2[(s * 32 + q * 8 + jj) * DOUT + m]);
    }
}

// ---------------------------------------------------------------------------
// Merged launch (R23 structure): gemm1 (blocks [0,GB)) runs CONCURRENTLY
// with the edge bucketing pass (blocks [GB, GB+BB)). Bucket path is the
// proven single-pass register-rank form; only the cntb atomic target is
// line-padded (R27).
// ---------------------------------------------------------------------------
__global__ __launch_bounds__(256) void k_g1bkt(const float* __restrict__ x,
                                               const unsigned short* __restrict__ w1frag,
                                               unsigned char* __restrict__ h1f8,
                                               float* __restrict__ al1sd,
                                               unsigned short* __restrict__ al1s8,
                                               const int* __restrict__ ei,
                                               int* __restrict__ cntb,
                                               unsigned* __restrict__ ebuf) {
    __shared__ int hist[4][NB];
    __shared__ int base[4][NB];
    int bid = blockIdx.x;
    if (bid < GB) {
        // ---- gemm1 path (MFMA, operand-swapped; fp8 h1 + fp32/bf16 logits) ----
        int wid = (bid * 256 + threadIdx.x) >> 6;
        int lane = threadIdx.x & 63;
        if (wid >= NW1) return;
        int nb = wid * 16;
        int m = lane & 15, quad = lane >> 4;
        const float* xrow = x + (nb + m) * DIN;

        float4 xf[8];
        #pragma unroll
        for (int s = 0; s < 4; s++) {
            xf[2 * s]     = *(const float4*)(xrow + s * 32 + quad * 8);
            xf[2 * s + 1] = *(const float4*)(xrow + s * 32 + quad * 8 + 4);
        }
        short8 bfr[4];
        #pragma unroll
        for (int s = 0; s < 4; s++) {
            unsigned short* bp = (unsigned short*)&bfr[s];
            float4 f0 = xf[2 * s], f1 = xf[2 * s + 1];
            bp[0] = f2bf(f0.x); bp[1] = f2bf(f0.y); bp[2] = f2bf(f0.z); bp[3] = f2bf(f0.w);
            bp[4] = f2bf(f1.x); bp[5] = f2bf(f1.y); bp[6] = f2bf(f1.z); bp[7] = f2bf(f1.w);
        }

        float4v acc[17];
        #pragma unroll
        for (int c = 0; c < 17; c++) acc[c] = (float4v){0.f, 0.f, 0.f, 0.f};

        #pragma unroll
        for (int s = 0; s < 4; s++) {
            const unsigned short* fp = w1frag + (s * 64 + lane) * 8;
            #pragma unroll
            for (int c = 0; c < 17; c++) {
                short8 afrag = *(const short8*)(fp + c * 2048);
                acc[c] = __builtin_amdgcn_mfma_f32_16x16x32_bf16(afrag, bfr[s], acc[c], 0, 0, 0);
            }
        }

        int node = nb + m;
        #pragma unroll
        for (int c = 0; c < 16; c++) {
            unsigned pk = 0;
            pk = __builtin_amdgcn_cvt_pk_fp8_f32(acc[c][0], acc[c][1], pk, false);
            pk = __builtin_amdgcn_cvt_pk_fp8_f32(acc[c][2], acc[c][3], pk, true);
            *(unsigned*)(h1f8 + node * C1 + c * 16 + quad * 4) = pk;
        }
        *(float4*)(al1sd + node * 16 + quad * 4) =
            make_float4(acc[16][0], acc[16][1], acc[16][2], acc[16][3]);
        if (quad < 2) {   // src logits (rows 0-7) packed bf16 -- 16 B/node table
            uint2 pk;
            pk.x = (unsigned)f2bf(acc[16][0]) | ((unsigned)f2bf(acc[16][1]) << 16);
            pk.y = (unsigned)f2bf(acc[16][2]) | ((unsigned)f2bf(acc[16][3]) << 16);
            *(uint2*)(al1s8 + node * 8 + quad * 4) = pk;
        }
    } else {
        // ---- bucket path: bucket edges by dst>>8; entry (src<<8)|(dst&255) ----
        int t = threadIdx.x;
        int wave = t >> 6;
        for (int i = t; i < 4 * NB; i += 256) ((int*)hist)[i] = 0;
        __syncthreads();
        int e0 = (bid - GB) * BBLK;
        int s[EPT], d[EPT], r[EPT];
        #pragma unroll
        for (int j = 0; j < EPT; j++) {
            int e = e0 + j * 256 + t;
            int ss = 0, dd = -1;
            if (e < EE) { ss = ei[e]; dd = ei[EE + e]; }
            else if (e < EP) { ss = e - EE; dd = ss; }   // self loop
            s[j] = ss; d[j] = dd;
            if (dd >= 0) r[j] = atomicAdd(&hist[wave][dd >> SH], 1);
        }
        __syncthreads();
        if (t < NB) {
            int h0 = hist[0][t], h1 = hist[1][t], h2 = hist[2][t], h3 = hist[3][t];
            int tot = h0 + h1 + h2 + h3;
            int bb = tot ? atomicAdd(&cntb[t * CSTR], tot) : 0;   // padded line
            base[0][t] = bb;
            base[1][t] = bb + h0;
            base[2][t] = bb + h0 + h1;
            base[3][t] = bb + h0 + h1 + h2;
        }
        __syncthreads();
        #pragma unroll
        for (int j = 0; j < EPT; j++) {
            if (d[j] >= 0) {
                int b = d[j] >> SH;
                ebuf[b * CAP + base[wave][b] + r[j]] =
                    ((unsigned)s[j] << SH) | (unsigned)(d[j] & 255);
            }
        }
    }
}

// ---------------------------------------------------------------------------
// CSR pass 2: one block per bucket; LDS count -> scan -> rank scatter.
// (cntb reads use the padded stride.)
// ---------------------------------------------------------------------------
__global__ __launch_bounds__(1024) void k_csr(const int* __restrict__ cntb,
                                              const unsigned* __restrict__ ebuf,
                                              int* __restrict__ row_ptr,
                                              int* __restrict__ esrc) {
    __shared__ int sdeg[256];
    __shared__ int wtot[4];
    __shared__ int bpart[4];
    int b = blockIdx.x;
    int t = threadIdx.x;
    int lane = t & 63, wave = t >> 6;
    int nodes0 = b << SH;
    if (t < 256) sdeg[t] = 0;
    if (t < 256) {
        int v = (t < b) ? cntb[t * CSTR] : 0;
        #pragma unroll
        for (int off = 1; off < 64; off <<= 1) v += __shfl_xor(v, off, 64);
        if (lane == 0) bpart[wave] = v;
    }
    __syncthreads();
    int baseS = bpart[0] + bpart[1] + bpart[2] + bpart[3];
    int cnt = cntb[b * CSTR];
    const unsigned* eb = ebuf + b * CAP;
    for (int i = t; i < cnt; i += 1024)
        atomicAdd(&sdeg[eb[i] & 255], 1);
    __syncthreads();
    int v = (t < 256) ? sdeg[t] : 0;
    int inc = v;
    #pragma unroll
    for (int off = 1; off < 64; off <<= 1) {
        int u = __shfl_up(inc, off, 64);
        if (lane >= off) inc += u;
    }
    if (t < 256 && lane == 63) wtot[wave] = inc;
    __syncthreads();
    if (wave == 0 && lane < 4) {
        int w = wtot[lane];
        int iw = w;
        #pragma unroll
        for (int off = 1; off < 4; off <<= 1) {
            int u = __shfl_up(iw, off, 64);
            if (lane >= off) iw += u;
        }
        wtot[lane] = iw - w;   // exclusive
    }
    __syncthreads();
    int excl = inc - v + ((t < 256) ? wtot[wave] : 0);
    __syncthreads();
    if (t < 256) {
        sdeg[t] = excl;
        int node = nodes0 + t;
        if (node < NN) row_ptr[node] = baseS + excl;
    }
    __syncthreads();
    for (int i = t; i < cnt; i += 1024) {
        unsigned e = eb[i];
        int pos = atomicAdd(&sdeg[e & 255], 1);
        esrc[baseS + pos] = (int)(e >> SH);
    }
    if (b == 0 && t == 0) row_ptr[NN] = EP;
}

// ---------------------------------------------------------------------------
// agg1 (R22, unchanged): hoisted producer gathers + readlane consumer.
// ---------------------------------------------------------------------------
__global__ __launch_bounds__(256) void k_agg1(const int* __restrict__ row_ptr,
                                              const int* __restrict__ esrc,
                                              const unsigned short* __restrict__ al1s8,
                                              const float* __restrict__ al1sd,
                                              const unsigned char* __restrict__ h1f8,
                                              const float* __restrict__ b1,
                                              unsigned short* __restrict__ helu_b) {
    int L = threadIdx.x & 63;
    int d = __builtin_amdgcn_readfirstlane((int)((blockIdx.x * 256 + threadIdx.x) >> 6));
    int start = row_ptr[d], end = row_ptr[d + 1];
    const int Lofs = L * 4;
    const int hprod = L & 7;             // producer head
    const int egrp  = L >> 3;            // producer edge-slot / consumer head
    float ald_p = al1sd[d * 16 + 8 + hprod];
    float denom = 0.f;
    float4 acc = make_float4(0.f, 0.f, 0.f, 0.f);

    for (int base = start; base < end; base += 32) {
        int cnt = min(32, end - base);            // wave-uniform
        int sval = d;
        if (L < cnt) sval = esrc[base + L];
        // --- hoisted producer gathers: all 4 groups' src logits in flight ---
        float asv0, asv1, asv2, asv3;
        {
            int sp0 = __shfl(sval, 0 * 8 + egrp, 64);
            int sp1 = __shfl(sval, 1 * 8 + egrp, 64);
            int sp2 = __shfl(sval, 2 * 8 + egrp, 64);
            int sp3 = __shfl(sval, 3 * 8 + egrp, 64);
            asv0 = bf2f(al1s8[sp0 * 8 + hprod]);
            asv1 = bf2f(al1s8[sp1 * 8 + hprod]);
            asv2 = bf2f(al1s8[sp2 * 8 + hprod]);
            asv3 = bf2f(al1s8[sp3 * 8 + hprod]);
        }
        #define AGG1_GROUP(K, ASV)                                              \
        if (cnt > (K) * 8) {                                                    \
            float e = (ASV) + ald_p;                                            \
            e = e > 0.f ? e : 0.2f * e;                                         \
            float w = ((K) * 8 + egrp < cnt) ? __expf(e) : 0.f;                 \
            unsigned v[8];                                                      \
            float xw[8];                                                        \
            _Pragma("unroll")                                                   \
            for (int j = 0; j < 8; j++) {                                       \
                int sj = __builtin_amdgcn_readlane(sval, (K) * 8 + j);          \
                v[j] = *(const unsigned*)(h1f8 + sj * C1 + Lofs);               \
                xw[j] = __shfl(w, j * 8 + egrp, 64);                            \
            }                                                                   \
            _Pragma("unroll")                                                   \
            for (int j = 0; j < 8; j++) {                                       \
                float2v a = __builtin_amdgcn_cvt_pk_f32_fp8(v[j], false);       \
                float2v b = __builtin_amdgcn_cvt_pk_f32_fp8(v[j], true);        \
                float xj = xw[j];                                               \
                denom += xj;                                                    \
                acc.x += xj * a.x; acc.y += xj * a.y;                           \
                acc.z += xj * b.x; acc.w += xj * b.y;                           \
            }                                                                   \
        }
        AGG1_GROUP(0, asv0)
        AGG1_GROUP(1, asv1)
        AGG1_GROUP(2, asv2)
        AGG1_GROUP(3, asv3)
        #undef AGG1_GROUP
    }
    float inv = 1.0f / (denom + 1e-16f);
    float4 bv = *(const float4*)(b1 + Lofs);
    float o0 = acc.x * inv + bv.x;
    float o1 = acc.y * inv + bv.y;
    float o2 = acc.z * inv + bv.z;
    float o3 = acc.w * inv + bv.w;
    o0 = o0 > 0.f ? o0 : __expf(o0) - 1.0f;
    o1 = o1 > 0.f ? o1 : __expf(o1) - 1.0f;
    o2 = o2 > 0.f ? o2 : __expf(o2) - 1.0f;
    o3 = o3 > 0.f ? o3 : __expf(o3) - 1.0f;
    uint2 pk;
    pk.x = (unsigned)f2bf(o0) | ((unsigned)f2bf(o1) << 16);
    pk.y = (unsigned)f2bf(o2) | ((unsigned)f2bf(o3) << 16);
    *(uint2*)(helu_b + d * C1 + Lofs) = pk;
}

// ---------------------------------------------------------------------------
// GEMM2 via MFMA + fused al2 epilogue (w2frag fragment-image B loads).
// ---------------------------------------------------------------------------
__global__ __launch_bounds__(256) void k_gemm2(const unsigned short* __restrict__ helu_b,
                                               const unsigned short* __restrict__ w2frag,
                                               const float* __restrict__ a2s,
                                               const float* __restrict__ a2d,
                                               unsigned short* __restrict__ h2b,
                                               float* __restrict__ al2s,
                                               float* __restrict__ al2d) {
    int wid = (blockIdx.x * 256 + threadIdx.x) >> 6;
    int lane = threadIdx.x & 63;
    int nb = wid * 16;
    if (nb >= NN) return;
    int m = lane & 15, quad = lane >> 4;

    const unsigned short* wp2 = w2frag + lane * 8;
    float4v acc = {0.f, 0.f, 0.f, 0.f};
    const unsigned short* arow = helu_b + (nb + m) * C1 + quad * 8;
    #pragma unroll
    for (int s = 0; s < 8; s++) {
        short8 afrag = *(const short8*)(arow + s * 32);
        short8 bfrag = *(const short8*)(wp2 + s * 512);
        acc = __builtin_amdgcn_mfma_f32_16x16x32_bf16(afrag, bfrag, acc, 0, 0, 0);
    }

    float as_c = a2s[m], ad_c = a2d[m];
    #pragma unroll
    for (int r = 0; r < 4; r++) {
        int node = nb + quad * 4 + r;
        float val = acc[r];
        h2b[node * DOUT + m] = f2bf(val);
        float ps = val * as_c;
        float pd = val * ad_c;
        ps += __shfl_xor(ps, 1, 64); ps += __shfl_xor(ps, 2, 64);
        ps += __shfl_xor(ps, 4, 64); ps += __shfl_xor(ps, 8, 64);
        pd += __shfl_xor(pd, 1, 64); pd += __shfl_xor(pd, 2, 64);
        pd += __shfl_xor(pd, 4, 64); pd += __shfl_xor(pd, 8, 64);
        if (m == 0) {
            al2s[node] = ps;
            al2d[node] = pd;
        }
    }
}

// ---------------------------------------------------------------------------
// agg2 + bias + log_softmax (R23 zero-LDS form, unchanged).
// ---------------------------------------------------------------------------
__global__ __launch_bounds__(256) void k_agg2(const int* __restrict__ row_ptr,
                                              const int* __restrict__ esrc,
                                              const unsigned short* __restrict__ h2b,
                                              const float* __restrict__ al2s,
                                              const float* __restrict__ al2d,
                                              const float* __restrict__ b2,
                                              float* __restrict__ out) {
    int L = threadIdx.x & 63;
    int n = __builtin_amdgcn_readfirstlane((int)((blockIdx.x * 256 + threadIdx.x) >> 6));
    int p = L & 7, g = L >> 3;          // channel-pair, edge-slot
    int start = row_ptr[n], end = row_ptr[n + 1];
    float ald = al2d[n];
    float acc0 = 0.f, acc1 = 0.f, denom = 0.f;

    for (int base = start; base < end; base += 64) {
        int cnt = min(64, end - base);            // wave-uniform
        int sval = n; float w = 0.f;
        if (L < cnt) {
            sval = esrc[base + L];
            float e = al2s[sval] + ald;
            e = e > 0.f ? e : 0.2f * e;
            w = __expf(e);
        }
        unsigned v0, v1, v2, v3, v4, v5, v6, v7;
        float w0, w1, w2, w3, w4, w5, w6, w7;
        #define AGG2_LOAD(K, V, W)                                             \
        if (cnt > (K) * 8) {                                                   \
            int ss = __shfl(sval, (K) * 8 + g, 64);                            \
            W = __shfl(w, (K) * 8 + g, 64);                                    \
            V = *(const unsigned*)(h2b + ss * DOUT + p * 2);                   \
        }
        AGG2_LOAD(0, v0, w0) AGG2_LOAD(1, v1, w1)
        AGG2_LOAD(2, v2, w2) AGG2_LOAD(3, v3, w3)
        AGG2_LOAD(4, v4, w4) AGG2_LOAD(5, v5, w5)
        AGG2_LOAD(6, v6, w6) AGG2_LOAD(7, v7, w7)
        #undef AGG2_LOAD
        #define AGG2_ACC(K, V, W)                                              \
        if (cnt > (K) * 8) {                                                   \
            acc0 += W * bflo(V); acc1 += W * bfhi(V); denom += W;              \
        }
        AGG2_ACC(0, v0, w0) AGG2_ACC(1, v1, w1)
        AGG2_ACC(2, v2, w2) AGG2_ACC(3, v3, w3)
        AGG2_ACC(4, v4, w4) AGG2_ACC(5, v5, w5)
        AGG2_ACC(6, v6, w6) AGG2_ACC(7, v7, w7)
        #undef AGG2_ACC
    }
    acc0 += __shfl_xor(acc0, 8, 64);  acc0 += __shfl_xor(acc0, 16, 64);  acc0 += __shfl_xor(acc0, 32, 64);
    acc1 += __shfl_xor(acc1, 8, 64);  acc1 += __shfl_xor(acc1, 16, 64);  acc1 += __shfl_xor(acc1, 32, 64);
    denom += __shfl_xor(denom, 8, 64); denom += __shfl_xor(denom, 16, 64); denom += __shfl_xor(denom, 32, 64);
    float inv = 1.0f / (denom + 1e-16f);
    float2 bv = *(const float2*)(b2 + p * 2);
    float val0 = acc0 * inv + bv.x;
    float val1 = acc1 * inv + bv.y;
    float m = fmaxf(val0, val1);
    #pragma unroll
    for (int mm = 1; mm < 8; mm <<= 1) m = fmaxf(m, __shfl_xor(m, mm, 64));
    float se = __expf(val0 - m) + __expf(val1 - m);
    #pragma unroll
    for (int mm = 1; mm < 8; mm <<= 1) se += __shfl_xor(se, mm, 64);
    float lse = m + __logf(se);
    if (L < 8) {
        float2 o = make_float2(val0 - lse, val1 - lse);
        *(float2*)(out + n * DOUT + p * 2) = o;
    }
}

// ---------------------------------------------------------------------------
extern "C" void kernel_launch(void* const* d_in, const int* in_sizes, int n_in,
                              void* d_out, int out_size, void* d_ws, size_t ws_size,
                              hipStream_t stream) {
    const float* x   = (const float*)d_in[0];
    const int*   ei  = (const int*)d_in[1];
    const float* W1  = (const float*)d_in[2];
    const float* a1s = (const float*)d_in[3];
    const float* a1d = (const float*)d_in[4];
    const float* b1  = (const float*)d_in[5];
    const float* W2  = (const float*)d_in[6];
    const float* a2s = (const float*)d_in[7];
    const float* a2d = (const float*)d_in[8];
    const float* b2  = (const float*)d_in[9];
    float* outp = (float*)d_out;

    // workspace layout
    unsigned char* h1f8    = (unsigned char*)d_ws;       // N*256 fp8 e4m3 (12.8 MB)
    unsigned short* helu_b = (unsigned short*)(h1f8 + NN * C1);  // N*256 bf16 (25.6 MB)
    unsigned short* h2b    = helu_b + NN * C1;           // N*16 bf16
    unsigned short* w2frag = h2b + NN * DOUT;            // 4096 bf16 (frag order)
    unsigned short* w1frag = w2frag + 8 * 512;           // 34816 bf16
    unsigned short* al1s8  = w1frag + 17 * 2048;         // N*8 bf16 (src logits)
    float* al1sd = (float*)(al1s8 + NN * 8);             // N*16 fp32
    float* al2sb = al1sd + NN * 16;                      // N
    float* al2db = al2sb + NN;                           // N
    int* row_ptr = (int*)(al2db + NN);                   // N+1
    int* esrc    = row_ptr + NN + 1;                     // EP
    int* cntb    = esrc + EP;                            // NB*CSTR (padded)
    // ebuf (packed ints, 6.4 MB) aliases helu_b (25.6 MB); consumed by k_csr
    // before agg1 writes helu_b -- stream ordering guarantees it.
    unsigned* ebuf = (unsigned*)helu_b;                  // NB * CAP uint

    // chain: prep -> {gemm1 || bucket} -> csr -> agg1 -> gemm2 -> agg2
    k_prepfw<<<(17 * 2048 + 8 * 512 + 255) / 256, 256, 0, stream>>>(W1, a1s, a1d, W2, w1frag, w2frag, cntb);
    k_g1bkt<<<GB + BB, 256, 0, stream>>>(x, w1frag, h1f8, al1sd, al1s8, ei, cntb, ebuf);
    k_csr<<<NB, 1024, 0, stream>>>(cntb, ebuf, row_ptr, esrc);
    k_agg1<<<12500, 256, 0, stream>>>(row_ptr, esrc, al1s8, al1sd, h1f8, b1, helu_b);
    k_gemm2<<<(NW1 * 64 + 255) / 256, 256, 0, stream>>>(helu_b, w2frag, a2s, a2d, h2b, al2sb, al2db);
    k_agg2<<<(NN * 64 + 255) / 256, 256, 0, stream>>>(row_ptr, esrc, h2b, al2sb, al2db, b2, outp);
}